// Round 5
// baseline (942.358 us; speedup 1.0000x reference)
//
#include <hip/hip_runtime.h>
#include <hip/hip_bf16.h>
#include <math.h>

using bf16 = __hip_bfloat16;
typedef __attribute__((ext_vector_type(8))) short short8;
typedef __attribute__((ext_vector_type(4))) float f32x4;

constexpr int Bc = 4, Sc = 4096, Dc = 1024, Hc = 16, DHc = 64, Fc = 64, DFFc = 4096;
constexpr float EPS_LN_C = 1e-5f, EPS_ATTN_C = 1e-6f;
constexpr int KVSPLIT = 16;

static __device__ __forceinline__ float b2f(bf16 v) { return __bfloat162float(v); }
static __device__ __forceinline__ bf16 f2b(float f) { return __float2bfloat16(f); }

// ---------------- block reduction (256 threads, wave64) ----------------
__device__ float block_reduce_sum(float v) {
  __shared__ float red[4];
  int lane = threadIdx.x & 63, wid = threadIdx.x >> 6;
#pragma unroll
  for (int off = 32; off > 0; off >>= 1) v += __shfl_down(v, off, 64);
  __syncthreads();
  if (lane == 0) red[wid] = v;
  __syncthreads();
  return red[0] + red[1] + red[2] + red[3];
}

// ---------------- LayerNorm: one block per row (D=1024) ----------------
__global__ void ln_kernel(const float* __restrict__ x, const float* __restrict__ g,
                          const float* __restrict__ bta, bf16* __restrict__ out) {
  int row = blockIdx.x;
  const float* xr = x + (size_t)row * Dc;
  int t = threadIdx.x;
  float v[4];
#pragma unroll
  for (int i = 0; i < 4; ++i) v[i] = xr[t + 256 * i];
  float s = block_reduce_sum(v[0] + v[1] + v[2] + v[3]);
  float mu = s * (1.f / Dc);
  float vs = 0.f;
#pragma unroll
  for (int i = 0; i < 4; ++i) { float d = v[i] - mu; vs += d * d; }
  vs = block_reduce_sum(vs);
  float rstd = rsqrtf(vs * (1.f / Dc) + EPS_LN_C);
  bf16* orow = out + (size_t)row * Dc;
#pragma unroll
  for (int i = 0; i < 4; ++i) {
    int c = t + 256 * i;
    orow[c] = f2b((v[i] - mu) * rstd * g[c] + bta[c]);
  }
}

// ------------- transpose + convert: in f32 [K,N] -> out bf16 [N,K] -------------
__global__ void tcvt_kernel(const float* __restrict__ in, bf16* __restrict__ out,
                            int K, int N) {
  __shared__ float t[32][33];
  int n0 = blockIdx.x * 32, k0 = blockIdx.y * 32;
  int tid = threadIdx.x;
#pragma unroll
  for (int i = 0; i < 4; ++i) {
    int idx = tid + 256 * i;
    int r = idx >> 5, c = idx & 31;
    t[r][c] = in[(size_t)(k0 + r) * N + n0 + c];
  }
  __syncthreads();
#pragma unroll
  for (int i = 0; i < 4; ++i) {
    int idx = tid + 256 * i;
    int r = idx >> 5, c = idx & 31;
    out[(size_t)(n0 + r) * K + k0 + c] = f2b(t[c][r]);
  }
}

// ====== 256x256 MFMA GEMM, BK=32 4-slot ring, reg-dbuf pipelined loop ======
// C[M,N] = A(bf16)[M,lda] * Bt(bf16)[N,ldbt]^T
// 512 threads = 8 waves (2M x 4N), per-wave 128x64 output (acc[8][4]).
// LDS ring: 4 slots x (A[256][32]+B[256][32]) = 128 KiB.
// Per subtile s (ONE barrier, no phase split):
//   vmcnt(4)  -> own loads for s+1 landed (stage for s+2 stays in flight)
//   s_barrier -> publishes s+1 resident to all waves; victim slot (s-1) drained
//   stage(s+3)            [4 global_load_lds, slot (s+3)&3 = old (s-1)]
//   ds_read subtile s+1 -> NXT frag regs  [12 b128; no manual lgkm wait]
//   32 MFMA on CUR frag regs              [compiler inserts counted lgkmcnt]
// -> intra-wave overlap of LDS reads + DMA with the MFMA cluster.
// LDS bank swizzle (proven r3, 0 conflicts): phys 16B-chunk = chunk ^ ((row>>1)&3),
// applied on the global SOURCE (linear gload_lds dest) and on ds_read addrs.
// EPI: 0 bf16 store | 1 f32 +bias+res | 2 bf16 gelu(+bias) | 3 f32 +(bias?)+res
//      4 QKV split: col c -> outB + (c>>10)*TOK*1024, col c&1023

template <int EPI>
__global__ __launch_bounds__(512, 2)
void mgemm256_kernel(const ushort* __restrict__ A, const ushort* __restrict__ Bt,
                     const float* __restrict__ bias, const float* __restrict__ res,
                     float* __restrict__ outF, bf16* __restrict__ outB,
                     int M, int N, int K, int lda, int ldbt) {
  constexpr int SLOT = 256 * 32;       // ushorts per slot per operand (16 KiB)
  __shared__ ushort AsR[4][SLOT];
  __shared__ ushort BsR[4][SLOT];
  const int tid = threadIdx.x;
  const int wave = tid >> 6, lane = tid & 63;
  const int wr = wave >> 2, wc = wave & 3;
  const int mrow = lane & 15, quad = lane >> 4;

  int nn = gridDim.x, nm = gridDim.y;
  int bid = blockIdx.y * nn + blockIdx.x;
  int mtile, ntile;
  if ((nm & 7) == 0) {          // XCD swizzle (bijection; perf-only heuristic)
    int xcd = bid & 7, s = bid >> 3;
    int mpx = nm >> 3;
    int mloc = s / nn;
    ntile = s - mloc * nn;
    mtile = xcd * mpx + mloc;
  } else { mtile = blockIdx.y; ntile = blockIdx.x; }
  const int row0 = mtile * 256, col0 = ntile * 256;

  // staging: linear LDS dest (tid*16B within 128-row half), inverse-swizzled src.
  const int srowL = tid >> 2;                                   // 0..127
  const int sOff = (((tid & 3) ^ ((tid >> 3) & 3)) << 3);       // ushort units
  const ushort* aB = A + (size_t)(row0 + srowL) * lda + sOff;
  const ushort* bB = Bt + (size_t)(col0 + srowL) * ldbt + sOff;
  const int dst = tid * 8;                                      // ushort units

  auto stage = [&](int sg) {
    const int sl = sg & 3;
#pragma unroll
    for (int l = 0; l < 2; ++l) {
      __builtin_amdgcn_global_load_lds(
          (const __attribute__((address_space(1))) void*)(aB + (size_t)(l * 128) * lda + sg * 32),
          (__attribute__((address_space(3))) void*)(&AsR[sl][l * 4096 + dst]), 16, 0, 0);
      __builtin_amdgcn_global_load_lds(
          (const __attribute__((address_space(1))) void*)(bB + (size_t)(l * 128) * ldbt + sg * 32),
          (__attribute__((address_space(3))) void*)(&BsR[sl][l * 4096 + dst]), 16, 0, 0);
    }
  };

  // ds_read swizzled chunk offset (ushort units): (quad ^ ((mrow>>1)&3)) * 8
  const int cq = (quad << 3) ^ (((mrow >> 1) & 3) << 3);
  const int arow = wr * 128 + mrow;
  const int brow = wc * 64 + mrow;

  f32x4 acc[8][4] = {};
  const int NS = K >> 5;  // BK=32 sub-tiles

  short8 fx[12], fy[12];  // frag sets: [0..7]=A, [8..11]=B

  auto dsread = [&](int sl, short8 (&f)[12]) {
    const ushort* As_ = &AsR[sl][0];
    const ushort* Bs_ = &BsR[sl][0];
#pragma unroll
    for (int i = 0; i < 8; ++i)
      f[i] = *(const short8*)(As_ + (arow + i * 16) * 32 + cq);
#pragma unroll
    for (int j = 0; j < 4; ++j)
      f[8 + j] = *(const short8*)(Bs_ + (brow + j * 16) * 32 + cq);
  };

  auto iter = [&](int s, short8 (&cur)[12], short8 (&nxt)[12]) {
    if (s + 2 < NS) asm volatile("s_waitcnt vmcnt(4)" ::: "memory");
    else            asm volatile("s_waitcnt vmcnt(0)" ::: "memory");
    __builtin_amdgcn_s_barrier();
    asm volatile("" ::: "memory");
    if (s + 3 < NS) stage(s + 3);
    if (s + 1 < NS) dsread((s + 1) & 3, nxt);
    __builtin_amdgcn_s_setprio(1);
#pragma unroll
    for (int i = 0; i < 8; ++i)
#pragma unroll
      for (int j = 0; j < 4; ++j)
        acc[i][j] = __builtin_amdgcn_mfma_f32_16x16x32_bf16(cur[i], cur[8 + j], acc[i][j], 0, 0, 0);
    __builtin_amdgcn_s_setprio(0);
  };

  // prologue: stage 0,1,2 (12 loads); wait own subtile-0 loads; publish
  stage(0); stage(1); stage(2);
  asm volatile("s_waitcnt vmcnt(8)" ::: "memory");
  __builtin_amdgcn_s_barrier();
  asm volatile("" ::: "memory");
  dsread(0, fx);

  for (int s = 0; s < NS; s += 2) {
    iter(s, fx, fy);
    iter(s + 1, fy, fx);
  }

  // epilogue
#pragma unroll
  for (int i = 0; i < 8; ++i) {
#pragma unroll
    for (int j = 0; j < 4; ++j) {
      int rb = row0 + wr * 128 + i * 16 + quad * 4;
      int c = col0 + wc * 64 + j * 16 + mrow;
#pragma unroll
      for (int r = 0; r < 4; ++r) {
        int rr = rb + r;
        float v = acc[i][j][r];
        if (EPI == 1 || EPI == 2) v += bias[c];
        if (EPI == 3) { if (bias) v += bias[c]; }
        if (EPI == 2) v = 0.5f * v * (1.f + erff(v * 0.70710678118654752f));
        if (EPI == 1 || EPI == 3) v += res[(size_t)rr * N + c];
        if (EPI == 4) {
          outB[((size_t)(c >> 10) * (size_t)(Bc * Sc) + rr) * 1024 + (c & 1023)] = f2b(v);
        } else if (EPI == 0 || EPI == 2) {
          outB[(size_t)rr * N + c] = f2b(v);
        } else {
          outF[(size_t)rr * N + c] = v;
        }
      }
    }
  }
}

// ======== fm_mfma: per-head [256s x 64] @ projT[64f][64d]^T, relu+eps ========
__global__ __launch_bounds__(256, 2)
void fm_mfma(const ushort* __restrict__ qin, const ushort* __restrict__ pjt,
             bf16* __restrict__ qf) {
  __shared__ ushort As[256 * 64];   // [s_local][d]
  __shared__ ushort Bs[64 * 64];    // [f][d]
  int t = threadIdx.x;
  int wave = t >> 6, lane = t & 63;
  int mrow = lane & 15, quad = lane >> 4;
  int b = blockIdx.z, h = blockIdx.y, s0 = blockIdx.x * 256;
  const ushort* abase = qin + ((size_t)b * Sc + s0) * (Hc * DHc) + h * DHc;

#pragma unroll
  for (int i = 0; i < 8; ++i) {
    int c = t + 256 * i;
    int row = c >> 3, col = (c & 7) * 8;
    __builtin_amdgcn_global_load_lds(
        (const __attribute__((address_space(1))) void*)(abase + (size_t)row * (Hc * DHc) + col),
        (__attribute__((address_space(3))) void*)(As + c * 8), 16, 0, 0);
  }
#pragma unroll
  for (int i = 0; i < 2; ++i) {
    int c = t + 256 * i;
    __builtin_amdgcn_global_load_lds(
        (const __attribute__((address_space(1))) void*)(pjt + c * 8),
        (__attribute__((address_space(3))) void*)(Bs + c * 8), 16, 0, 0);
  }
  __syncthreads();

  f32x4 acc[4][4] = {};
#pragma unroll
  for (int step = 0; step < 2; ++step) {
    short8 af[4], bfv[4];
#pragma unroll
    for (int i = 0; i < 4; ++i)
      af[i] = *(const short8*)(As + (wave * 64 + i * 16 + mrow) * 64 + quad * 8 + step * 32);
#pragma unroll
    for (int j = 0; j < 4; ++j)
      bfv[j] = *(const short8*)(Bs + (j * 16 + mrow) * 64 + quad * 8 + step * 32);
#pragma unroll
    for (int i = 0; i < 4; ++i)
#pragma unroll
      for (int j = 0; j < 4; ++j)
        acc[i][j] = __builtin_amdgcn_mfma_f32_16x16x32_bf16(af[i], bfv[j], acc[i][j], 0, 0, 0);
  }

  size_t obase = ((size_t)(b * Hc + h)) * Sc + s0;
#pragma unroll
  for (int i = 0; i < 4; ++i) {
#pragma unroll
    for (int j = 0; j < 4; ++j) {
      int f = j * 16 + mrow;
#pragma unroll
      for (int r = 0; r < 4; ++r) {
        int s = wave * 64 + i * 16 + quad * 4 + r;
        float v = fmaxf(acc[i][j][r], 0.f) + EPS_ATTN_C;
        qf[(obase + s) * Fc + f] = f2b(v);
      }
    }
  }
}

// ======== kvp_mfma: split-K kf^T v (+ ksum) via LDS transpose ========
__global__ __launch_bounds__(256, 2)
void kvp_mfma(const ushort* __restrict__ kf, const ushort* __restrict__ v,
              float* __restrict__ kvp, float* __restrict__ ksump) {
  constexpr int LT = 72;
  __shared__ ushort kfT[64 * LT];   // [f][s]
  __shared__ ushort vT[64 * LT];    // [d][s]
  int t = threadIdx.x;
  int wave = t >> 6, lane = t & 63;
  int mrow = lane & 15, quad = lane >> 4;
  int split = blockIdx.x, bh = blockIdx.y;
  int b = bh >> 4, h = bh & 15;
  int sbase = split * (Sc / KVSPLIT);

  short8 ones, zero;
#pragma unroll
  for (int i = 0; i < 8; ++i) { ones[i] = (short)0x3F80; zero[i] = 0; }
  short8 bks = (mrow == 0) ? ones : zero;

  f32x4 acc[4] = {};
  f32x4 accks = {};

  for (int sc = 0; sc < Sc / KVSPLIT; sc += 64) {
    __syncthreads();
    int sl = t >> 2, c8 = (t & 3) * 8;
    const ushort* kp = kf + (((size_t)bh * Sc) + sbase + sc + sl) * Fc + c8;
    const ushort* vp = v + (((size_t)b * Sc) + sbase + sc + sl) * (Hc * DHc) + h * DHc + c8;
#pragma unroll
    for (int half = 0; half < 2; ++half) {
      short8 kv8 = *(const short8*)(kp + half * 32);
      short8 vv8 = *(const short8*)(vp + half * 32);
#pragma unroll
      for (int jj = 0; jj < 8; ++jj) {
        kfT[(c8 + half * 32 + jj) * LT + sl] = (ushort)kv8[jj];
        vT[(c8 + half * 32 + jj) * LT + sl] = (ushort)vv8[jj];
      }
    }
    __syncthreads();
#pragma unroll
    for (int step = 0; step < 2; ++step) {
      short8 af = *(const short8*)(kfT + (wave * 16 + mrow) * LT + quad * 8 + step * 32);
      short8 bfv[4];
#pragma unroll
      for (int j = 0; j < 4; ++j)
        bfv[j] = *(const short8*)(vT + (j * 16 + mrow) * LT + quad * 8 + step * 32);
#pragma unroll
      for (int j = 0; j < 4; ++j)
        acc[j] = __builtin_amdgcn_mfma_f32_16x16x32_bf16(af, bfv[j], acc[j], 0, 0, 0);
      accks = __builtin_amdgcn_mfma_f32_16x16x32_bf16(af, bks, accks, 0, 0, 0);
    }
  }

  size_t pbase = (size_t)bh * KVSPLIT + split;
#pragma unroll
  for (int j = 0; j < 4; ++j) {
    int d = j * 16 + mrow;
#pragma unroll
    for (int r = 0; r < 4; ++r) {
      int f = wave * 16 + quad * 4 + r;
      kvp[(pbase * 64 + f) * 64 + d] = acc[j][r];
    }
  }
  if (mrow == 0) {
#pragma unroll
    for (int r = 0; r < 4; ++r) {
      int f = wave * 16 + quad * 4 + r;
      ksump[pbase * 64 + f] = accks[r];
    }
  }
}

// ------- kv reduce: sums KVSPLIT partials -> kvt bf16 [d][f], ksum bf16 -------
__global__ void kvr_kernel(const float* __restrict__ kvp, const float* __restrict__ ksump,
                           bf16* __restrict__ kvt, bf16* __restrict__ ksum16) {
  int bh = blockIdx.x;
  int t = threadIdx.x;
#pragma unroll
  for (int i = 0; i < 16; ++i) {
    int idx = t + 256 * i;
    int f = idx >> 6, d = idx & 63;
    float s = 0.f;
#pragma unroll
    for (int j = 0; j < KVSPLIT; ++j)
      s += kvp[((size_t)bh * KVSPLIT + j) * 4096 + idx];
    kvt[((size_t)bh * 64 + d) * 64 + f] = f2b(s);
  }
  if (t < 64) {
    float s = 0.f;
#pragma unroll
    for (int j = 0; j < KVSPLIT; ++j)
      s += ksump[((size_t)bh * KVSPLIT + j) * 64 + t];
    ksum16[bh * 64 + t] = f2b(s);
  }
}

// ======== attn_mfma: per-head (qf @ kv) / (qf.ksum + eps) ========
__global__ __launch_bounds__(256, 2)
void attn_mfma(const ushort* __restrict__ qf, const ushort* __restrict__ kvt,
               const ushort* __restrict__ ksum16, bf16* __restrict__ attn) {
  __shared__ ushort As[256 * 64];   // [s_local][f]
  __shared__ ushort Bs[64 * 64];    // [d][f]
  int t = threadIdx.x;
  int wave = t >> 6, lane = t & 63;
  int mrow = lane & 15, quad = lane >> 4;
  int b = blockIdx.z, h = blockIdx.y, s0 = blockIdx.x * 256;
  int bh = b * Hc + h;
  const ushort* abase = qf + (((size_t)bh * Sc) + s0) * Fc;
  const ushort* bbase = kvt + (size_t)bh * 4096;

#pragma unroll
  for (int i = 0; i < 8; ++i) {
    int c = t + 256 * i;
    __builtin_amdgcn_global_load_lds(
        (const __attribute__((address_space(1))) void*)(abase + c * 8),
        (__attribute__((address_space(3))) void*)(As + c * 8), 16, 0, 0);
  }
#pragma unroll
  for (int i = 0; i < 2; ++i) {
    int c = t + 256 * i;
    __builtin_amdgcn_global_load_lds(
        (const __attribute__((address_space(1))) void*)(bbase + c * 8),
        (__attribute__((address_space(3))) void*)(Bs + c * 8), 16, 0, 0);
  }
  short8 zero;
#pragma unroll
  for (int i = 0; i < 8; ++i) zero[i] = 0;
  short8 ksf[2];
#pragma unroll
  for (int step = 0; step < 2; ++step) {
    short8 kv8 = *(const short8*)(ksum16 + bh * 64 + quad * 8 + step * 32);
    ksf[step] = (mrow == 0) ? kv8 : zero;
  }
  __syncthreads();

  f32x4 acc[4][4] = {};
  f32x4 accd[4] = {};
#pragma unroll
  for (int step = 0; step < 2; ++step) {
    short8 af[4], bfv[4];
#pragma unroll
    for (int i = 0; i < 4; ++i)
      af[i] = *(const short8*)(As + (wave * 64 + i * 16 + mrow) * 64 + quad * 8 + step * 32);
#pragma unroll
    for (int j = 0; j < 4; ++j)
      bfv[j] = *(const short8*)(Bs + (j * 16 + mrow) * 64 + quad * 8 + step * 32);
#pragma unroll
    for (int i = 0; i < 4; ++i) {
#pragma unroll
      for (int j = 0; j < 4; ++j)
        acc[i][j] = __builtin_amdgcn_mfma_f32_16x16x32_bf16(af[i], bfv[j], acc[i][j], 0, 0, 0);
      accd[i] = __builtin_amdgcn_mfma_f32_16x16x32_bf16(af[i], ksf[step], accd[i], 0, 0, 0);
    }
  }

#pragma unroll
  for (int i = 0; i < 4; ++i) {
    float inv[4];
#pragma unroll
    for (int r = 0; r < 4; ++r) {
      float den = __shfl(accd[i][r], lane & 48);
      inv[r] = 1.0f / (den + EPS_ATTN_C);
    }
#pragma unroll
    for (int j = 0; j < 4; ++j) {
      int d = j * 16 + mrow;
#pragma unroll
      for (int r = 0; r < 4; ++r) {
        int s = s0 + wave * 64 + i * 16 + quad * 4 + r;
        attn[((size_t)(b * Sc + s)) * (Hc * DHc) + h * DHc + d] = f2b(acc[i][j][r] * inv[r]);
      }
    }
  }
}

extern "C" void kernel_launch(void* const* d_in, const int* in_sizes, int n_in,
                              void* d_out, int out_size, void* d_ws, size_t ws_size,
                              hipStream_t stream) {
  const float* x     = (const float*)d_in[0];
  const float* ln1_g = (const float*)d_in[1];
  const float* ln1_b = (const float*)d_in[2];
  const float* wq    = (const float*)d_in[3];
  const float* wk    = (const float*)d_in[4];
  const float* wv    = (const float*)d_in[5];
  const float* proj  = (const float*)d_in[6];
  const float* wo    = (const float*)d_in[7];
  const float* bo    = (const float*)d_in[8];
  const float* ln2_g = (const float*)d_in[9];
  const float* ln2_b = (const float*)d_in[10];
  const float* w1    = (const float*)d_in[11];
  const float* b1    = (const float*)d_in[12];
  const float* w2    = (const float*)d_in[13];
  const float* b2    = (const float*)d_in[14];
  float* out = (float*)d_out;
  (void)ws_size; (void)in_sizes; (void)n_in; (void)out_size;

  const size_t TOK = (size_t)Bc * Sc;           // 16384
  const size_t REG = TOK * Dc * sizeof(bf16);   // 32 MB
  char* ws = (char*)d_ws;
  bf16* R0 = (bf16*)(ws + 0 * REG);             // h -> qf -> h2
  bf16* R1 = (bf16*)(ws + 1 * REG);             // q -> kf -> mid(lo)
  bf16* R2 = (bf16*)(ws + 2 * REG);             // k -> [kv partials] -> attn -> mid(hi)
  bf16* R3 = (bf16*)(ws + 3 * REG);             // v
  bf16* mid = R1;
  float* kvpart = (float*)R2;                                   // 16 MB (aliases R2)
  float* kspart = (float*)((char*)R2 + (size_t)64 * KVSPLIT * 4096 * 4);
  char* p = ws + 4 * REG;
  bf16* kvt   = (bf16*)p;                 p += (size_t)64 * 64 * 64 * 2;
  bf16* ksb16 = (bf16*)p;                 p += (size_t)64 * 64 * 2;
  bf16* pjt   = (bf16*)p;                 p += (size_t)64 * 64 * 2;
  bf16* wqt = (bf16*)p;                   p += (size_t)Dc * Dc * 2;   // wqt/wkt/wvt contiguous:
  bf16* wkt = (bf16*)p;                   p += (size_t)Dc * Dc * 2;   // single [3072][1024] Bt slab
  bf16* wvt = (bf16*)p;                   p += (size_t)Dc * Dc * 2;
  bf16* wot = (bf16*)p;                   p += (size_t)Dc * Dc * 2;
  bf16* w1t = (bf16*)p;                   p += (size_t)Dc * DFFc * 2;
  bf16* w2t = (bf16*)p;                   p += (size_t)Dc * DFFc * 2;

  dim3 blk(256);
  dim3 blk512(512);
  // 0. transpose+convert weights (and proj) to bf16 B^T form
  tcvt_kernel<<<dim3(Dc / 32, Dc / 32), blk, 0, stream>>>(wq, wqt, Dc, Dc);
  tcvt_kernel<<<dim3(Dc / 32, Dc / 32), blk, 0, stream>>>(wk, wkt, Dc, Dc);
  tcvt_kernel<<<dim3(Dc / 32, Dc / 32), blk, 0, stream>>>(wv, wvt, Dc, Dc);
  tcvt_kernel<<<dim3(Dc / 32, Dc / 32), blk, 0, stream>>>(wo, wot, Dc, Dc);
  tcvt_kernel<<<dim3(DFFc / 32, Dc / 32), blk, 0, stream>>>(w1, w1t, Dc, DFFc);
  tcvt_kernel<<<dim3(Dc / 32, DFFc / 32), blk, 0, stream>>>(w2, w2t, DFFc, Dc);
  tcvt_kernel<<<dim3(2, 2), blk, 0, stream>>>(proj, pjt, 64, 64);

  // 1. h = LN1(x) -> R0
  ln_kernel<<<dim3(TOK), blk, 0, stream>>>(x, ln1_g, ln1_b, R0);

  // 2. fused QKV: [TOK,1024] @ [3072,1024]^T -> split into R1,R2,R3 (EPI=4)
  dim3 gQKV(3072 / 256, TOK / 256);
  mgemm256_kernel<4><<<gQKV, blk512, 0, stream>>>((const ushort*)R0, (const ushort*)wqt,
                                                  nullptr, nullptr, nullptr, R1,
                                                  TOK, 3072, Dc, Dc, Dc);

  // 5-6. qf = fm(q): R1 -> R0 ; kf = fm(k): R2 -> R1
  dim3 gF(Sc / 256, Hc, Bc);
  fm_mfma<<<gF, blk, 0, stream>>>((const ushort*)R1, (const ushort*)pjt, R0);
  fm_mfma<<<gF, blk, 0, stream>>>((const ushort*)R2, (const ushort*)pjt, R1);

  // 7. kv partials + reduce
  kvp_mfma<<<dim3(KVSPLIT, Bc * Hc), blk, 0, stream>>>((const ushort*)R1, (const ushort*)R3,
                                                       kvpart, kspart);
  kvr_kernel<<<dim3(Bc * Hc), blk, 0, stream>>>(kvpart, kspart, kvt, ksb16);

  // 8. attn: qf(R0) x kvt -> R2
  attn_mfma<<<gF, blk, 0, stream>>>((const ushort*)R0, (const ushort*)kvt,
                                    (const ushort*)ksb16, R2);

  // 9. x2 = x + attn @ wo + bo -> d_out (f32)
  dim3 gD(Dc / 256, TOK / 256);
  mgemm256_kernel<1><<<gD, blk512, 0, stream>>>((const ushort*)R2, (const ushort*)wot, bo, x,
                                                out, nullptr, TOK, Dc, Dc, Dc, Dc);

  // 10. h2 = LN2(x2) -> R0
  ln_kernel<<<dim3(TOK), blk, 0, stream>>>(out, ln2_g, ln2_b, R0);

  // 11-12. FFN in two DFF halves (mid aliases R1+R2)
  dim3 gW1(2048 / 256, TOK / 256);
  mgemm256_kernel<2><<<gW1, blk512, 0, stream>>>((const ushort*)R0, (const ushort*)w1t, b1, nullptr,
                                                 nullptr, mid, TOK, 2048, Dc, Dc, Dc);
  mgemm256_kernel<3><<<gD, blk512, 0, stream>>>((const ushort*)mid, (const ushort*)w2t, b2, out,
                                                out, nullptr, TOK, Dc, 2048, 2048, DFFc);
  mgemm256_kernel<2><<<gW1, blk512, 0, stream>>>((const ushort*)R0, (const ushort*)(w1t + (size_t)2048 * Dc), b1 + 2048,
                                                 nullptr, nullptr, mid, TOK, 2048, Dc, Dc, Dc);
  mgemm256_kernel<3><<<gD, blk512, 0, stream>>>((const ushort*)mid, (const ushort*)(w2t + 2048), nullptr, out,
                                                out, nullptr, TOK, Dc, 2048, 2048, DFFc);
}

// Round 6
// 839.067 us; speedup vs baseline: 1.1231x; 1.1231x over previous
//
#include <hip/hip_runtime.h>
#include <hip/hip_bf16.h>
#include <math.h>

using bf16 = __hip_bfloat16;
typedef __attribute__((ext_vector_type(8))) short short8;
typedef __attribute__((ext_vector_type(4))) float f32x4;

constexpr int Bc = 4, Sc = 4096, Dc = 1024, Hc = 16, DHc = 64, Fc = 64, DFFc = 4096;
constexpr float EPS_LN_C = 1e-5f, EPS_ATTN_C = 1e-6f;
constexpr int KVSPLIT = 16;

static __device__ __forceinline__ float b2f(bf16 v) { return __bfloat162float(v); }
static __device__ __forceinline__ bf16 f2b(float f) { return __float2bfloat16(f); }

// ---------------- block reduction (256 threads, wave64) ----------------
__device__ float block_reduce_sum(float v) {
  __shared__ float red[4];
  int lane = threadIdx.x & 63, wid = threadIdx.x >> 6;
#pragma unroll
  for (int off = 32; off > 0; off >>= 1) v += __shfl_down(v, off, 64);
  __syncthreads();
  if (lane == 0) red[wid] = v;
  __syncthreads();
  return red[0] + red[1] + red[2] + red[3];
}

// ---------------- LayerNorm: one block per row (D=1024) ----------------
__global__ void ln_kernel(const float* __restrict__ x, const float* __restrict__ g,
                          const float* __restrict__ bta, bf16* __restrict__ out) {
  int row = blockIdx.x;
  const float* xr = x + (size_t)row * Dc;
  int t = threadIdx.x;
  float v[4];
#pragma unroll
  for (int i = 0; i < 4; ++i) v[i] = xr[t + 256 * i];
  float s = block_reduce_sum(v[0] + v[1] + v[2] + v[3]);
  float mu = s * (1.f / Dc);
  float vs = 0.f;
#pragma unroll
  for (int i = 0; i < 4; ++i) { float d = v[i] - mu; vs += d * d; }
  vs = block_reduce_sum(vs);
  float rstd = rsqrtf(vs * (1.f / Dc) + EPS_LN_C);
  bf16* orow = out + (size_t)row * Dc;
#pragma unroll
  for (int i = 0; i < 4; ++i) {
    int c = t + 256 * i;
    orow[c] = f2b((v[i] - mu) * rstd * g[c] + bta[c]);
  }
}

// ------------- transpose + convert: in f32 [K,N] -> out bf16 [N,K] -------------
__global__ void tcvt_kernel(const float* __restrict__ in, bf16* __restrict__ out,
                            int K, int N) {
  __shared__ float t[32][33];
  int n0 = blockIdx.x * 32, k0 = blockIdx.y * 32;
  int tid = threadIdx.x;
#pragma unroll
  for (int i = 0; i < 4; ++i) {
    int idx = tid + 256 * i;
    int r = idx >> 5, c = idx & 31;
    t[r][c] = in[(size_t)(k0 + r) * N + n0 + c];
  }
  __syncthreads();
#pragma unroll
  for (int i = 0; i < 4; ++i) {
    int idx = tid + 256 * i;
    int r = idx >> 5, c = idx & 31;
    out[(size_t)(n0 + r) * K + k0 + c] = f2b(t[c][r]);
  }
}

// ---------------- MFMA GEMM: C[M,N] = A(bf16)[M,lda] * Bt(bf16)[N,ldbt]^T ------
// Round-0 TLP structure (128x128 tile, 256 thr = 4 waves of 64x64, multi-block
// occupancy, plain __syncthreads staging) with two deltas:
//  - BK=64: one staging round + 2 barriers per 64 of K (32 MFMA/wave/barrier)
//  - r3-proven conflict-free LDS: two [128][32] sub-tiles, 16B-chunk swizzle
//    phys = chunk ^ ((row>>1)&3), inverse-applied on the global source
//    (linear global_load_lds dest) and on ds_read addrs. Measured 0 conflicts.
// EPI: 0 bf16 store | 1 f32 +bias+res | 2 bf16 gelu(+bias) | 3 f32 +(bias?)+res
//      4 QKV split: col c -> outB + (c>>10)*TOK*1024, col c&1023
template <int EPI>
__global__ __launch_bounds__(256, 2)
void mgemm_kernel(const ushort* __restrict__ A, const ushort* __restrict__ Bt,
                  const float* __restrict__ bias, const float* __restrict__ res,
                  float* __restrict__ outF, bf16* __restrict__ outB,
                  int M, int N, int K, int lda, int ldbt) {
  __shared__ ushort As[2][128 * 32];   // [k-substep][row*32+col]
  __shared__ ushort Bs[2][128 * 32];
  int tid = threadIdx.x;
  int wave = tid >> 6, lane = tid & 63;
  int wm = (wave >> 1) * 64, wn = (wave & 1) * 64;
  int mrow = lane & 15, quad = lane >> 4;

  int nn = gridDim.x, nm = gridDim.y;
  int bid = blockIdx.y * nn + blockIdx.x;
  int mtile, ntile;
  if ((nm & 7) == 0) {          // XCD swizzle (bijection; perf-only heuristic)
    int xcd = bid & 7, s = bid >> 3;
    int mpx = nm >> 3;
    int mloc = s / nn;
    ntile = s - mloc * nn;
    mtile = xcd * mpx + mloc;
  } else { mtile = blockIdx.y; ntile = blockIdx.x; }
  int row0 = mtile * 128, col0 = ntile * 128;

  // staging: pass l covers rows l*64 + (tid>>2); phys 16B-chunk tid&3 holds
  // logical chunk (tid&3)^((row>>1)&3) = (tid&3)^((tid>>3)&3)  [l*64 ≡ 0 mod 4]
  const int srow = tid >> 2;                                  // 0..63
  const int scol = (((tid & 3) ^ ((tid >> 3) & 3)) << 3);     // ushort units
  const ushort* aP = A + (size_t)(row0 + srow) * lda + scol;
  const ushort* bP = Bt + (size_t)(col0 + srow) * ldbt + scol;
  const int dst = tid * 8;                                    // ushort units

  f32x4 acc[4][4] = {};

  // ds_read swizzled chunk offset: (quad ^ ((mrow>>1)&3)) * 8 ushorts
  const int cq = ((quad ^ ((mrow >> 1) & 3)) << 3);

  for (int k0 = 0; k0 < K; k0 += 64) {
    __syncthreads();
#pragma unroll
    for (int st = 0; st < 2; ++st) {
#pragma unroll
      for (int l = 0; l < 2; ++l) {
        __builtin_amdgcn_global_load_lds(
            (const __attribute__((address_space(1))) void*)(aP + (size_t)(l * 64) * lda + k0 + st * 32),
            (__attribute__((address_space(3))) void*)(&As[st][l * 2048 + dst]), 16, 0, 0);
        __builtin_amdgcn_global_load_lds(
            (const __attribute__((address_space(1))) void*)(bP + (size_t)(l * 64) * ldbt + k0 + st * 32),
            (__attribute__((address_space(3))) void*)(&Bs[st][l * 2048 + dst]), 16, 0, 0);
      }
    }
    __syncthreads();

    short8 af[2][4], bfv[2][4];
#pragma unroll
    for (int st = 0; st < 2; ++st) {
#pragma unroll
      for (int i = 0; i < 4; ++i)
        af[st][i] = *(const short8*)(&As[st][(wm + i * 16 + mrow) * 32 + cq]);
#pragma unroll
      for (int j = 0; j < 4; ++j)
        bfv[st][j] = *(const short8*)(&Bs[st][(wn + j * 16 + mrow) * 32 + cq]);
    }
#pragma unroll
    for (int i = 0; i < 4; ++i)
#pragma unroll
      for (int j = 0; j < 4; ++j) {
        acc[i][j] = __builtin_amdgcn_mfma_f32_16x16x32_bf16(af[0][i], bfv[0][j], acc[i][j], 0, 0, 0);
        acc[i][j] = __builtin_amdgcn_mfma_f32_16x16x32_bf16(af[1][i], bfv[1][j], acc[i][j], 0, 0, 0);
      }
  }

#pragma unroll
  for (int i = 0; i < 4; ++i) {
#pragma unroll
    for (int j = 0; j < 4; ++j) {
      int rb = row0 + wm + i * 16 + quad * 4;
      int c = col0 + wn + j * 16 + mrow;
#pragma unroll
      for (int r = 0; r < 4; ++r) {
        int rr = rb + r;
        float v = acc[i][j][r];
        if (EPI == 1 || EPI == 2) v += bias[c];
        if (EPI == 3) { if (bias) v += bias[c]; }
        if (EPI == 2) v = 0.5f * v * (1.f + erff(v * 0.70710678118654752f));
        if (EPI == 1 || EPI == 3) v += res[(size_t)rr * N + c];
        if (EPI == 4) {
          outB[((size_t)(c >> 10) * (size_t)(Bc * Sc) + rr) * 1024 + (c & 1023)] = f2b(v);
        } else if (EPI == 0 || EPI == 2) {
          outB[(size_t)rr * N + c] = f2b(v);
        } else {
          outF[(size_t)rr * N + c] = v;
        }
      }
    }
  }
}

// ======== fm_mfma: per-head [256s x 64] @ projT[64f][64d]^T, relu+eps ========
__global__ __launch_bounds__(256, 2)
void fm_mfma(const ushort* __restrict__ qin, const ushort* __restrict__ pjt,
             bf16* __restrict__ qf) {
  __shared__ ushort As[256 * 64];   // [s_local][d]
  __shared__ ushort Bs[64 * 64];    // [f][d]
  int t = threadIdx.x;
  int wave = t >> 6, lane = t & 63;
  int mrow = lane & 15, quad = lane >> 4;
  int b = blockIdx.z, h = blockIdx.y, s0 = blockIdx.x * 256;
  const ushort* abase = qin + ((size_t)b * Sc + s0) * (Hc * DHc) + h * DHc;

#pragma unroll
  for (int i = 0; i < 8; ++i) {
    int c = t + 256 * i;
    int row = c >> 3, col = (c & 7) * 8;
    __builtin_amdgcn_global_load_lds(
        (const __attribute__((address_space(1))) void*)(abase + (size_t)row * (Hc * DHc) + col),
        (__attribute__((address_space(3))) void*)(As + c * 8), 16, 0, 0);
  }
#pragma unroll
  for (int i = 0; i < 2; ++i) {
    int c = t + 256 * i;
    __builtin_amdgcn_global_load_lds(
        (const __attribute__((address_space(1))) void*)(pjt + c * 8),
        (__attribute__((address_space(3))) void*)(Bs + c * 8), 16, 0, 0);
  }
  __syncthreads();

  f32x4 acc[4][4] = {};
#pragma unroll
  for (int step = 0; step < 2; ++step) {
    short8 af[4], bfv[4];
#pragma unroll
    for (int i = 0; i < 4; ++i)
      af[i] = *(const short8*)(As + (wave * 64 + i * 16 + mrow) * 64 + quad * 8 + step * 32);
#pragma unroll
    for (int j = 0; j < 4; ++j)
      bfv[j] = *(const short8*)(Bs + (j * 16 + mrow) * 64 + quad * 8 + step * 32);
#pragma unroll
    for (int i = 0; i < 4; ++i)
#pragma unroll
      for (int j = 0; j < 4; ++j)
        acc[i][j] = __builtin_amdgcn_mfma_f32_16x16x32_bf16(af[i], bfv[j], acc[i][j], 0, 0, 0);
  }

  size_t obase = ((size_t)(b * Hc + h)) * Sc + s0;
#pragma unroll
  for (int i = 0; i < 4; ++i) {
#pragma unroll
    for (int j = 0; j < 4; ++j) {
      int f = j * 16 + mrow;
#pragma unroll
      for (int r = 0; r < 4; ++r) {
        int s = wave * 64 + i * 16 + quad * 4 + r;
        float v = fmaxf(acc[i][j][r], 0.f) + EPS_ATTN_C;
        qf[(obase + s) * Fc + f] = f2b(v);
      }
    }
  }
}

// ======== kvp_mfma: split-K kf^T v (+ ksum) via LDS transpose ========
__global__ __launch_bounds__(256, 2)
void kvp_mfma(const ushort* __restrict__ kf, const ushort* __restrict__ v,
              float* __restrict__ kvp, float* __restrict__ ksump) {
  constexpr int LT = 72;
  __shared__ ushort kfT[64 * LT];   // [f][s]
  __shared__ ushort vT[64 * LT];    // [d][s]
  int t = threadIdx.x;
  int wave = t >> 6, lane = t & 63;
  int mrow = lane & 15, quad = lane >> 4;
  int split = blockIdx.x, bh = blockIdx.y;
  int b = bh >> 4, h = bh & 15;
  int sbase = split * (Sc / KVSPLIT);

  short8 ones, zero;
#pragma unroll
  for (int i = 0; i < 8; ++i) { ones[i] = (short)0x3F80; zero[i] = 0; }
  short8 bks = (mrow == 0) ? ones : zero;

  f32x4 acc[4] = {};
  f32x4 accks = {};

  for (int sc = 0; sc < Sc / KVSPLIT; sc += 64) {
    __syncthreads();
    int sl = t >> 2, c8 = (t & 3) * 8;
    const ushort* kp = kf + (((size_t)bh * Sc) + sbase + sc + sl) * Fc + c8;
    const ushort* vp = v + (((size_t)b * Sc) + sbase + sc + sl) * (Hc * DHc) + h * DHc + c8;
#pragma unroll
    for (int half = 0; half < 2; ++half) {
      short8 kv8 = *(const short8*)(kp + half * 32);
      short8 vv8 = *(const short8*)(vp + half * 32);
#pragma unroll
      for (int jj = 0; jj < 8; ++jj) {
        kfT[(c8 + half * 32 + jj) * LT + sl] = (ushort)kv8[jj];
        vT[(c8 + half * 32 + jj) * LT + sl] = (ushort)vv8[jj];
      }
    }
    __syncthreads();
#pragma unroll
    for (int step = 0; step < 2; ++step) {
      short8 af = *(const short8*)(kfT + (wave * 16 + mrow) * LT + quad * 8 + step * 32);
      short8 bfv[4];
#pragma unroll
      for (int j = 0; j < 4; ++j)
        bfv[j] = *(const short8*)(vT + (j * 16 + mrow) * LT + quad * 8 + step * 32);
#pragma unroll
      for (int j = 0; j < 4; ++j)
        acc[j] = __builtin_amdgcn_mfma_f32_16x16x32_bf16(af, bfv[j], acc[j], 0, 0, 0);
      accks = __builtin_amdgcn_mfma_f32_16x16x32_bf16(af, bks, accks, 0, 0, 0);
    }
  }

  size_t pbase = (size_t)bh * KVSPLIT + split;
#pragma unroll
  for (int j = 0; j < 4; ++j) {
    int d = j * 16 + mrow;
#pragma unroll
    for (int r = 0; r < 4; ++r) {
      int f = wave * 16 + quad * 4 + r;
      kvp[(pbase * 64 + f) * 64 + d] = acc[j][r];
    }
  }
  if (mrow == 0) {
#pragma unroll
    for (int r = 0; r < 4; ++r) {
      int f = wave * 16 + quad * 4 + r;
      ksump[pbase * 64 + f] = accks[r];
    }
  }
}

// ------- kv reduce: sums KVSPLIT partials -> kvt bf16 [d][f], ksum bf16 -------
__global__ void kvr_kernel(const float* __restrict__ kvp, const float* __restrict__ ksump,
                           bf16* __restrict__ kvt, bf16* __restrict__ ksum16) {
  int bh = blockIdx.x;
  int t = threadIdx.x;
#pragma unroll
  for (int i = 0; i < 16; ++i) {
    int idx = t + 256 * i;
    int f = idx >> 6, d = idx & 63;
    float s = 0.f;
#pragma unroll
    for (int j = 0; j < KVSPLIT; ++j)
      s += kvp[((size_t)bh * KVSPLIT + j) * 4096 + idx];
    kvt[((size_t)bh * 64 + d) * 64 + f] = f2b(s);
  }
  if (t < 64) {
    float s = 0.f;
#pragma unroll
    for (int j = 0; j < KVSPLIT; ++j)
      s += ksump[((size_t)bh * KVSPLIT + j) * 64 + t];
    ksum16[bh * 64 + t] = f2b(s);
  }
}

// ======== attn_mfma: per-head (qf @ kv) / (qf.ksum + eps) ========
__global__ __launch_bounds__(256, 2)
void attn_mfma(const ushort* __restrict__ qf, const ushort* __restrict__ kvt,
               const ushort* __restrict__ ksum16, bf16* __restrict__ attn) {
  __shared__ ushort As[256 * 64];   // [s_local][f]
  __shared__ ushort Bs[64 * 64];    // [d][f]
  int t = threadIdx.x;
  int wave = t >> 6, lane = t & 63;
  int mrow = lane & 15, quad = lane >> 4;
  int b = blockIdx.z, h = blockIdx.y, s0 = blockIdx.x * 256;
  int bh = b * Hc + h;
  const ushort* abase = qf + (((size_t)bh * Sc) + s0) * Fc;
  const ushort* bbase = kvt + (size_t)bh * 4096;

#pragma unroll
  for (int i = 0; i < 8; ++i) {
    int c = t + 256 * i;
    __builtin_amdgcn_global_load_lds(
        (const __attribute__((address_space(1))) void*)(abase + c * 8),
        (__attribute__((address_space(3))) void*)(As + c * 8), 16, 0, 0);
  }
#pragma unroll
  for (int i = 0; i < 2; ++i) {
    int c = t + 256 * i;
    __builtin_amdgcn_global_load_lds(
        (const __attribute__((address_space(1))) void*)(bbase + c * 8),
        (__attribute__((address_space(3))) void*)(Bs + c * 8), 16, 0, 0);
  }
  short8 zero;
#pragma unroll
  for (int i = 0; i < 8; ++i) zero[i] = 0;
  short8 ksf[2];
#pragma unroll
  for (int step = 0; step < 2; ++step) {
    short8 kv8 = *(const short8*)(ksum16 + bh * 64 + quad * 8 + step * 32);
    ksf[step] = (mrow == 0) ? kv8 : zero;
  }
  __syncthreads();

  f32x4 acc[4][4] = {};
  f32x4 accd[4] = {};
#pragma unroll
  for (int step = 0; step < 2; ++step) {
    short8 af[4], bfv[4];
#pragma unroll
    for (int i = 0; i < 4; ++i)
      af[i] = *(const short8*)(As + (wave * 64 + i * 16 + mrow) * 64 + quad * 8 + step * 32);
#pragma unroll
    for (int j = 0; j < 4; ++j)
      bfv[j] = *(const short8*)(Bs + (j * 16 + mrow) * 64 + quad * 8 + step * 32);
#pragma unroll
    for (int i = 0; i < 4; ++i) {
#pragma unroll
      for (int j = 0; j < 4; ++j)
        acc[i][j] = __builtin_amdgcn_mfma_f32_16x16x32_bf16(af[i], bfv[j], acc[i][j], 0, 0, 0);
      accd[i] = __builtin_amdgcn_mfma_f32_16x16x32_bf16(af[i], ksf[step], accd[i], 0, 0, 0);
    }
  }

#pragma unroll
  for (int i = 0; i < 4; ++i) {
    float inv[4];
#pragma unroll
    for (int r = 0; r < 4; ++r) {
      float den = __shfl(accd[i][r], lane & 48);
      inv[r] = 1.0f / (den + EPS_ATTN_C);
    }
#pragma unroll
    for (int j = 0; j < 4; ++j) {
      int d = j * 16 + mrow;
#pragma unroll
      for (int r = 0; r < 4; ++r) {
        int s = s0 + wave * 64 + i * 16 + quad * 4 + r;
        attn[((size_t)(b * Sc + s)) * (Hc * DHc) + h * DHc + d] = f2b(acc[i][j][r] * inv[r]);
      }
    }
  }
}

extern "C" void kernel_launch(void* const* d_in, const int* in_sizes, int n_in,
                              void* d_out, int out_size, void* d_ws, size_t ws_size,
                              hipStream_t stream) {
  const float* x     = (const float*)d_in[0];
  const float* ln1_g = (const float*)d_in[1];
  const float* ln1_b = (const float*)d_in[2];
  const float* wq    = (const float*)d_in[3];
  const float* wk    = (const float*)d_in[4];
  const float* wv    = (const float*)d_in[5];
  const float* proj  = (const float*)d_in[6];
  const float* wo    = (const float*)d_in[7];
  const float* bo    = (const float*)d_in[8];
  const float* ln2_g = (const float*)d_in[9];
  const float* ln2_b = (const float*)d_in[10];
  const float* w1    = (const float*)d_in[11];
  const float* b1    = (const float*)d_in[12];
  const float* w2    = (const float*)d_in[13];
  const float* b2    = (const float*)d_in[14];
  float* out = (float*)d_out;
  (void)ws_size; (void)in_sizes; (void)n_in; (void)out_size;

  const size_t TOK = (size_t)Bc * Sc;           // 16384
  const size_t REG = TOK * Dc * sizeof(bf16);   // 32 MB
  char* ws = (char*)d_ws;
  bf16* R0 = (bf16*)(ws + 0 * REG);             // h -> qf -> h2
  bf16* R1 = (bf16*)(ws + 1 * REG);             // q -> kf -> mid(lo)
  bf16* R2 = (bf16*)(ws + 2 * REG);             // k -> [kv partials] -> attn -> mid(hi)
  bf16* R3 = (bf16*)(ws + 3 * REG);             // v
  bf16* mid = R1;
  float* kvpart = (float*)R2;                                   // 16 MB (aliases R2)
  float* kspart = (float*)((char*)R2 + (size_t)64 * KVSPLIT * 4096 * 4);
  char* p = ws + 4 * REG;
  bf16* kvt   = (bf16*)p;                 p += (size_t)64 * 64 * 64 * 2;
  bf16* ksb16 = (bf16*)p;                 p += (size_t)64 * 64 * 2;
  bf16* pjt   = (bf16*)p;                 p += (size_t)64 * 64 * 2;
  bf16* wqt = (bf16*)p;                   p += (size_t)Dc * Dc * 2;   // wqt/wkt/wvt contiguous:
  bf16* wkt = (bf16*)p;                   p += (size_t)Dc * Dc * 2;   // single [3072][1024] Bt slab
  bf16* wvt = (bf16*)p;                   p += (size_t)Dc * Dc * 2;
  bf16* wot = (bf16*)p;                   p += (size_t)Dc * Dc * 2;
  bf16* w1t = (bf16*)p;                   p += (size_t)Dc * DFFc * 2;
  bf16* w2t = (bf16*)p;                   p += (size_t)Dc * DFFc * 2;

  dim3 blk(256);
  // 0. transpose+convert weights (and proj) to bf16 B^T form
  tcvt_kernel<<<dim3(Dc / 32, Dc / 32), blk, 0, stream>>>(wq, wqt, Dc, Dc);
  tcvt_kernel<<<dim3(Dc / 32, Dc / 32), blk, 0, stream>>>(wk, wkt, Dc, Dc);
  tcvt_kernel<<<dim3(Dc / 32, Dc / 32), blk, 0, stream>>>(wv, wvt, Dc, Dc);
  tcvt_kernel<<<dim3(Dc / 32, Dc / 32), blk, 0, stream>>>(wo, wot, Dc, Dc);
  tcvt_kernel<<<dim3(DFFc / 32, Dc / 32), blk, 0, stream>>>(w1, w1t, Dc, DFFc);
  tcvt_kernel<<<dim3(Dc / 32, DFFc / 32), blk, 0, stream>>>(w2, w2t, DFFc, Dc);
  tcvt_kernel<<<dim3(2, 2), blk, 0, stream>>>(proj, pjt, 64, 64);

  // 1. h = LN1(x) -> R0
  ln_kernel<<<dim3(TOK), blk, 0, stream>>>(x, ln1_g, ln1_b, R0);

  // 2. fused QKV: [TOK,1024] @ [3072,1024]^T -> split into R1,R2,R3 (EPI=4)
  dim3 gQKV(3072 / 128, TOK / 128);
  mgemm_kernel<4><<<gQKV, blk, 0, stream>>>((const ushort*)R0, (const ushort*)wqt, nullptr, nullptr,
                                            nullptr, R1, TOK, 3072, Dc, Dc, Dc);

  // 5-6. qf = fm(q): R1 -> R0 ; kf = fm(k): R2 -> R1
  dim3 gF(Sc / 256, Hc, Bc);
  fm_mfma<<<gF, blk, 0, stream>>>((const ushort*)R1, (const ushort*)pjt, R0);
  fm_mfma<<<gF, blk, 0, stream>>>((const ushort*)R2, (const ushort*)pjt, R1);

  // 7. kv partials + reduce
  kvp_mfma<<<dim3(KVSPLIT, Bc * Hc), blk, 0, stream>>>((const ushort*)R1, (const ushort*)R3,
                                                       kvpart, kspart);
  kvr_kernel<<<dim3(Bc * Hc), blk, 0, stream>>>(kvpart, kspart, kvt, ksb16);

  // 8. attn: qf(R0) x kvt -> R2
  attn_mfma<<<gF, blk, 0, stream>>>((const ushort*)R0, (const ushort*)kvt,
                                    (const ushort*)ksb16, R2);

  // 9. x2 = x + attn @ wo + bo -> d_out (f32)
  dim3 gD(Dc / 128, TOK / 128);
  mgemm_kernel<1><<<gD, blk, 0, stream>>>((const ushort*)R2, (const ushort*)wot, bo, x,
                                          out, nullptr, TOK, Dc, Dc, Dc, Dc);

  // 10. h2 = LN2(x2) -> R0
  ln_kernel<<<dim3(TOK), blk, 0, stream>>>(out, ln2_g, ln2_b, R0);

  // 11-12. FFN in two DFF halves (mid aliases R1+R2)
  dim3 gW1(2048 / 128, TOK / 128);
  mgemm_kernel<2><<<gW1, blk, 0, stream>>>((const ushort*)R0, (const ushort*)w1t, b1, nullptr,
                                           nullptr, mid, TOK, 2048, Dc, Dc, Dc);
  mgemm_kernel<3><<<gD, blk, 0, stream>>>((const ushort*)mid, (const ushort*)w2t, b2, out,
                                          out, nullptr, TOK, Dc, 2048, 2048, DFFc);
  mgemm_kernel<2><<<gW1, blk, 0, stream>>>((const ushort*)R0, (const ushort*)(w1t + (size_t)2048 * Dc), b1 + 2048,
                                           nullptr, nullptr, mid, TOK, 2048, Dc, Dc, Dc);
  mgemm_kernel<3><<<gD, blk, 0, stream>>>((const ushort*)mid, (const ushort*)(w2t + 2048), nullptr, out,
                                          out, nullptr, TOK, Dc, 2048, 2048, DFFc);
}

// Round 8
// 838.791 us; speedup vs baseline: 1.1235x; 1.0003x over previous
//
#include <hip/hip_runtime.h>
#include <hip/hip_bf16.h>
#include <math.h>

using bf16 = __hip_bfloat16;
typedef __attribute__((ext_vector_type(8))) short short8;
typedef __attribute__((ext_vector_type(4))) short short4v;
typedef __attribute__((ext_vector_type(4))) float f32x4;

constexpr int Bc = 4, Sc = 4096, Dc = 1024, Hc = 16, DHc = 64, Fc = 64, DFFc = 4096;
constexpr float EPS_LN_C = 1e-5f, EPS_ATTN_C = 1e-6f;
constexpr int KVSPLIT = 16;

static __device__ __forceinline__ float b2f(bf16 v) { return __bfloat162float(v); }
static __device__ __forceinline__ bf16 f2b(float f) { return __float2bfloat16(f); }

// ---------------- block reduction (256 threads, wave64) ----------------
__device__ float block_reduce_sum(float v) {
  __shared__ float red[4];
  int lane = threadIdx.x & 63, wid = threadIdx.x >> 6;
#pragma unroll
  for (int off = 32; off > 0; off >>= 1) v += __shfl_down(v, off, 64);
  __syncthreads();
  if (lane == 0) red[wid] = v;
  __syncthreads();
  return red[0] + red[1] + red[2] + red[3];
}

// ---------------- LayerNorm: one block per row (D=1024), float4 vectorized ----
__global__ void ln_kernel(const float* __restrict__ x, const float* __restrict__ g,
                          const float* __restrict__ bta, bf16* __restrict__ out) {
  int row = blockIdx.x;
  int t = threadIdx.x;
  const float4* xr = (const float4*)(x + (size_t)row * Dc);
  float4 v4 = xr[t];
  float v[4] = {v4.x, v4.y, v4.z, v4.w};
  float s = block_reduce_sum(v[0] + v[1] + v[2] + v[3]);
  float mu = s * (1.f / Dc);
  float vs = 0.f;
#pragma unroll
  for (int i = 0; i < 4; ++i) { float d = v[i] - mu; vs += d * d; }
  vs = block_reduce_sum(vs);
  float rstd = rsqrtf(vs * (1.f / Dc) + EPS_LN_C);
  float4 g4 = ((const float4*)g)[t];
  float4 b4 = ((const float4*)bta)[t];
  float gg[4] = {g4.x, g4.y, g4.z, g4.w};
  float bb[4] = {b4.x, b4.y, b4.z, b4.w};
  short4v o;
#pragma unroll
  for (int i = 0; i < 4; ++i) {
    bf16 h = f2b((v[i] - mu) * rstd * gg[i] + bb[i]);
    o[i] = *(short*)&h;
  }
  *(short4v*)(out + (size_t)row * Dc + t * 4) = o;
}

// ------------- transpose + convert: in f32 [K,N] -> out bf16 [N,K] -------------
__global__ void tcvt_kernel(const float* __restrict__ in, bf16* __restrict__ out,
                            int K, int N) {
  __shared__ float t[32][33];
  int n0 = blockIdx.x * 32, k0 = blockIdx.y * 32;
  int tid = threadIdx.x;
#pragma unroll
  for (int i = 0; i < 4; ++i) {
    int idx = tid + 256 * i;
    int r = idx >> 5, c = idx & 31;
    t[r][c] = in[(size_t)(k0 + r) * N + n0 + c];
  }
  __syncthreads();
#pragma unroll
  for (int i = 0; i < 4; ++i) {
    int idx = tid + 256 * i;
    int r = idx >> 5, c = idx & 31;
    out[(size_t)(n0 + r) * K + k0 + c] = f2b(t[c][r]);
  }
}

// -------- tcvt_proj: fold proj into wq/wk, output Bt form bf16 ----------------
// out[(h*64+f)][k] = sum_d w[k][h*64+d] * proj[d][f]   (f32 accumulate)
// grid (Dc/64, Hc, 2): z=0 -> wq->wqpt, z=1 -> wk->wkpt. block 256.
__global__ void tcvt_proj_kernel(const float* __restrict__ wq, const float* __restrict__ wk,
                                 const float* __restrict__ proj,
                                 bf16* __restrict__ wqpt, bf16* __restrict__ wkpt) {
  __shared__ float wsl[64][65];   // [k][d] padded
  __shared__ float ps[64][64];    // [d][f]
  int t = threadIdx.x;
  int k0 = blockIdx.x * 64, h = blockIdx.y;
  const float* w = blockIdx.z ? wk : wq;
  bf16* outp = blockIdx.z ? wkpt : wqpt;
#pragma unroll
  for (int i = 0; i < 16; ++i) {
    int idx = t + 256 * i;
    int r = idx >> 6, c = idx & 63;
    wsl[r][c] = w[(size_t)(k0 + r) * (Hc * DHc) + h * DHc + c];
    ps[r][c] = proj[idx];
  }
  __syncthreads();
  int k = t & 63, fg = t >> 6;   // per-wave: all lanes share fg -> ps broadcast
  float acc[16];
#pragma unroll
  for (int i = 0; i < 16; ++i) acc[i] = 0.f;
  for (int d = 0; d < 64; ++d) {
    float wv = wsl[k][d];
#pragma unroll
    for (int i = 0; i < 16; ++i) acc[i] += wv * ps[d][fg * 16 + i];
  }
#pragma unroll
  for (int i = 0; i < 16; ++i)
    outp[(size_t)(h * 64 + fg * 16 + i) * Dc + k0 + k] = f2b(acc[i]);
}

// ---------------- MFMA GEMM: C[M,N] = A(bf16)[M,lda] * Bt(bf16)[N,ldbt]^T ------
// r6 verified structure: 128x128 tile, 4 waves, BK=64, conflict-free LDS swizzle
// (phys 16B-chunk = chunk ^ ((row>>1)&3), inverse on global src, measured 0 conf).
// EPI: 0 bf16 store | 1 f32 +bias+res | 2 bf16 gelu(+bias) | 3 f32 +bias+res
//      4 QKV split+fm: cols<2048 -> relu+eps, per-head layout [B,H,S,64] into
//          outB + buf*TOK*1024 (buf=c>>10); col>=2048 -> v token-major.
template <int EPI>
__global__ __launch_bounds__(256, 2)
void mgemm_kernel(const ushort* __restrict__ A, const ushort* __restrict__ Bt,
                  const float* __restrict__ bias, const float* __restrict__ res,
                  float* __restrict__ outF, bf16* __restrict__ outB,
                  int M, int N, int K, int lda, int ldbt) {
  __shared__ ushort As[2][128 * 32];   // [k-substep][row*32+col]
  __shared__ ushort Bs[2][128 * 32];
  int tid = threadIdx.x;
  int wave = tid >> 6, lane = tid & 63;
  int wm = (wave >> 1) * 64, wn = (wave & 1) * 64;
  int mrow = lane & 15, quad = lane >> 4;

  int nn = gridDim.x, nm = gridDim.y;
  int bid = blockIdx.y * nn + blockIdx.x;
  int mtile, ntile;
  if ((nm & 7) == 0) {          // XCD swizzle (bijection; perf-only heuristic)
    int xcd = bid & 7, s = bid >> 3;
    int mpx = nm >> 3;
    int mloc = s / nn;
    ntile = s - mloc * nn;
    mtile = xcd * mpx + mloc;
  } else { mtile = blockIdx.y; ntile = blockIdx.x; }
  int row0 = mtile * 128, col0 = ntile * 128;

  const int srow = tid >> 2;                                  // 0..63
  const int scol = (((tid & 3) ^ ((tid >> 3) & 3)) << 3);     // ushort units
  const ushort* aP = A + (size_t)(row0 + srow) * lda + scol;
  const ushort* bP = Bt + (size_t)(col0 + srow) * ldbt + scol;
  const int dst = tid * 8;                                    // ushort units

  f32x4 acc[4][4] = {};
  const int cq = ((quad ^ ((mrow >> 1) & 3)) << 3);

  for (int k0 = 0; k0 < K; k0 += 64) {
    __syncthreads();
#pragma unroll
    for (int st = 0; st < 2; ++st) {
#pragma unroll
      for (int l = 0; l < 2; ++l) {
        __builtin_amdgcn_global_load_lds(
            (const __attribute__((address_space(1))) void*)(aP + (size_t)(l * 64) * lda + k0 + st * 32),
            (__attribute__((address_space(3))) void*)(&As[st][l * 2048 + dst]), 16, 0, 0);
        __builtin_amdgcn_global_load_lds(
            (const __attribute__((address_space(1))) void*)(bP + (size_t)(l * 64) * ldbt + k0 + st * 32),
            (__attribute__((address_space(3))) void*)(&Bs[st][l * 2048 + dst]), 16, 0, 0);
      }
    }
    __syncthreads();

    short8 af[2][4], bfv[2][4];
#pragma unroll
    for (int st = 0; st < 2; ++st) {
#pragma unroll
      for (int i = 0; i < 4; ++i)
        af[st][i] = *(const short8*)(&As[st][(wm + i * 16 + mrow) * 32 + cq]);
#pragma unroll
      for (int j = 0; j < 4; ++j)
        bfv[st][j] = *(const short8*)(&Bs[st][(wn + j * 16 + mrow) * 32 + cq]);
    }
#pragma unroll
    for (int i = 0; i < 4; ++i)
#pragma unroll
      for (int j = 0; j < 4; ++j) {
        acc[i][j] = __builtin_amdgcn_mfma_f32_16x16x32_bf16(af[0][i], bfv[0][j], acc[i][j], 0, 0, 0);
        acc[i][j] = __builtin_amdgcn_mfma_f32_16x16x32_bf16(af[1][i], bfv[1][j], acc[i][j], 0, 0, 0);
      }
  }

#pragma unroll
  for (int i = 0; i < 4; ++i) {
#pragma unroll
    for (int j = 0; j < 4; ++j) {
      int rb = row0 + wm + i * 16 + quad * 4;
      int c = col0 + wn + j * 16 + mrow;
#pragma unroll
      for (int r = 0; r < 4; ++r) {
        int rr = rb + r;
        float v = acc[i][j][r];
        if (EPI == 1 || EPI == 2) v += bias[c];
        if (EPI == 3) { if (bias) v += bias[c]; }
        if (EPI == 2) v = 0.5f * v * (1.f + erff(v * 0.70710678118654752f));
        if (EPI == 1 || EPI == 3) v += res[(size_t)rr * N + c];
        if (EPI == 4) {
          int buf = c >> 10;
          size_t base = (size_t)buf * ((size_t)Bc * Sc * 1024);
          if (buf < 2) {   // q,k: relu+eps, per-head layout [B,H,S,64]
            float vv = fmaxf(v, 0.f) + EPS_ATTN_C;
            size_t bb = (size_t)(rr >> 12), ss = (size_t)(rr & 4095);
            int h = (c >> 6) & 15, f = c & 63;
            outB[base + ((bb * 16 + h) * 4096 + ss) * 64 + f] = f2b(vv);
          } else {         // v: token-major
            outB[base + (size_t)rr * 1024 + (c & 1023)] = f2b(v);
          }
        } else if (EPI == 0 || EPI == 2) {
          outB[(size_t)rr * N + c] = f2b(v);
        } else {
          outF[(size_t)rr * N + c] = v;
        }
      }
    }
  }
}

// ======== kvp_mfma: split-K kf^T v (+ ksum) via LDS transpose ========
__global__ __launch_bounds__(256, 2)
void kvp_mfma(const ushort* __restrict__ kf, const ushort* __restrict__ v,
              float* __restrict__ kvp, float* __restrict__ ksump) {
  constexpr int LT = 72;
  __shared__ ushort kfT[64 * LT];   // [f][s]
  __shared__ ushort vT[64 * LT];    // [d][s]
  int t = threadIdx.x;
  int wave = t >> 6, lane = t & 63;
  int mrow = lane & 15, quad = lane >> 4;
  int split = blockIdx.x, bh = blockIdx.y;
  int b = bh >> 4, h = bh & 15;
  int sbase = split * (Sc / KVSPLIT);

  short8 ones, zero;
#pragma unroll
  for (int i = 0; i < 8; ++i) { ones[i] = (short)0x3F80; zero[i] = 0; }
  short8 bks = (mrow == 0) ? ones : zero;

  f32x4 acc[4] = {};
  f32x4 accks = {};

  for (int sc = 0; sc < Sc / KVSPLIT; sc += 64) {
    __syncthreads();
    int sl = t >> 2, c8 = (t & 3) * 8;
    const ushort* kp = kf + (((size_t)bh * Sc) + sbase + sc + sl) * Fc + c8;
    const ushort* vp = v + (((size_t)b * Sc) + sbase + sc + sl) * (Hc * DHc) + h * DHc + c8;
#pragma unroll
    for (int half = 0; half < 2; ++half) {
      short8 kv8 = *(const short8*)(kp + half * 32);
      short8 vv8 = *(const short8*)(vp + half * 32);
#pragma unroll
      for (int jj = 0; jj < 8; ++jj) {
        kfT[(c8 + half * 32 + jj) * LT + sl] = (ushort)kv8[jj];
        vT[(c8 + half * 32 + jj) * LT + sl] = (ushort)vv8[jj];
      }
    }
    __syncthreads();
#pragma unroll
    for (int step = 0; step < 2; ++step) {
      short8 af = *(const short8*)(kfT + (wave * 16 + mrow) * LT + quad * 8 + step * 32);
      short8 bfv[4];
#pragma unroll
      for (int j = 0; j < 4; ++j)
        bfv[j] = *(const short8*)(vT + (j * 16 + mrow) * LT + quad * 8 + step * 32);
#pragma unroll
      for (int j = 0; j < 4; ++j)
        acc[j] = __builtin_amdgcn_mfma_f32_16x16x32_bf16(af, bfv[j], acc[j], 0, 0, 0);
      accks = __builtin_amdgcn_mfma_f32_16x16x32_bf16(af, bks, accks, 0, 0, 0);
    }
  }

  size_t pbase = (size_t)bh * KVSPLIT + split;
#pragma unroll
  for (int j = 0; j < 4; ++j) {
    int d = j * 16 + mrow;
#pragma unroll
    for (int r = 0; r < 4; ++r) {
      int f = wave * 16 + quad * 4 + r;
      kvp[(pbase * 64 + f) * 64 + d] = acc[j][r];
    }
  }
  if (mrow == 0) {
#pragma unroll
    for (int r = 0; r < 4; ++r) {
      int f = wave * 16 + quad * 4 + r;
      ksump[pbase * 64 + f] = accks[r];
    }
  }
}

// ------- kv reduce: sums KVSPLIT partials -> kvt bf16 [d][f], ksum bf16 -------
__global__ void kvr_kernel(const float* __restrict__ kvp, const float* __restrict__ ksump,
                           bf16* __restrict__ kvt, bf16* __restrict__ ksum16) {
  int bh = blockIdx.x;
  int t = threadIdx.x;
#pragma unroll
  for (int i = 0; i < 16; ++i) {
    int idx = t + 256 * i;
    int f = idx >> 6, d = idx & 63;
    float s = 0.f;
#pragma unroll
    for (int j = 0; j < KVSPLIT; ++j)
      s += kvp[((size_t)bh * KVSPLIT + j) * 4096 + idx];
    kvt[((size_t)bh * 64 + d) * 64 + f] = f2b(s);
  }
  if (t < 64) {
    float s = 0.f;
#pragma unroll
    for (int j = 0; j < KVSPLIT; ++j)
      s += ksump[((size_t)bh * KVSPLIT + j) * 64 + t];
    ksum16[bh * 64 + t] = f2b(s);
  }
}

// ======== attn_mfma: per-head (qf @ kv) / (qf.ksum + eps) ========
__global__ __launch_bounds__(256, 2)
void attn_mfma(const ushort* __restrict__ qf, const ushort* __restrict__ kvt,
               const ushort* __restrict__ ksum16, bf16* __restrict__ attn) {
  __shared__ ushort As[256 * 64];   // [s_local][f]
  __shared__ ushort Bs[64 * 64];    // [d][f]
  int t = threadIdx.x;
  int wave = t >> 6, lane = t & 63;
  int mrow = lane & 15, quad = lane >> 4;
  int b = blockIdx.z, h = blockIdx.y, s0 = blockIdx.x * 256;
  int bh = b * Hc + h;
  const ushort* abase = qf + (((size_t)bh * Sc) + s0) * Fc;
  const ushort* bbase = kvt + (size_t)bh * 4096;

#pragma unroll
  for (int i = 0; i < 8; ++i) {
    int c = t + 256 * i;
    __builtin_amdgcn_global_load_lds(
        (const __attribute__((address_space(1))) void*)(abase + c * 8),
        (__attribute__((address_space(3))) void*)(As + c * 8), 16, 0, 0);
  }
#pragma unroll
  for (int i = 0; i < 2; ++i) {
    int c = t + 256 * i;
    __builtin_amdgcn_global_load_lds(
        (const __attribute__((address_space(1))) void*)(bbase + c * 8),
        (__attribute__((address_space(3))) void*)(Bs + c * 8), 16, 0, 0);
  }
  short8 zero;
#pragma unroll
  for (int i = 0; i < 8; ++i) zero[i] = 0;
  short8 ksf[2];
#pragma unroll
  for (int step = 0; step < 2; ++step) {
    short8 kv8 = *(const short8*)(ksum16 + bh * 64 + quad * 8 + step * 32);
    ksf[step] = (mrow == 0) ? kv8 : zero;
  }
  __syncthreads();

  f32x4 acc[4][4] = {};
  f32x4 accd[4] = {};
#pragma unroll
  for (int step = 0; step < 2; ++step) {
    short8 af[4], bfv[4];
#pragma unroll
    for (int i = 0; i < 4; ++i)
      af[i] = *(const short8*)(As + (wave * 64 + i * 16 + mrow) * 64 + quad * 8 + step * 32);
#pragma unroll
    for (int j = 0; j < 4; ++j)
      bfv[j] = *(const short8*)(Bs + (j * 16 + mrow) * 64 + quad * 8 + step * 32);
#pragma unroll
    for (int i = 0; i < 4; ++i) {
#pragma unroll
      for (int j = 0; j < 4; ++j)
        acc[i][j] = __builtin_amdgcn_mfma_f32_16x16x32_bf16(af[i], bfv[j], acc[i][j], 0, 0, 0);
      accd[i] = __builtin_amdgcn_mfma_f32_16x16x32_bf16(af[i], ksf[step], accd[i], 0, 0, 0);
    }
  }

#pragma unroll
  for (int i = 0; i < 4; ++i) {
    float inv[4];
#pragma unroll
    for (int r = 0; r < 4; ++r) {
      float den = __shfl(accd[i][r], lane & 48);
      inv[r] = 1.0f / (den + EPS_ATTN_C);
    }
#pragma unroll
    for (int j = 0; j < 4; ++j) {
      int d = j * 16 + mrow;
#pragma unroll
      for (int r = 0; r < 4; ++r) {
        int s = s0 + wave * 64 + i * 16 + quad * 4 + r;
        attn[((size_t)(b * Sc + s)) * (Hc * DHc) + h * DHc + d] = f2b(acc[i][j][r] * inv[r]);
      }
    }
  }
}

extern "C" void kernel_launch(void* const* d_in, const int* in_sizes, int n_in,
                              void* d_out, int out_size, void* d_ws, size_t ws_size,
                              hipStream_t stream) {
  const float* x     = (const float*)d_in[0];
  const float* ln1_g = (const float*)d_in[1];
  const float* ln1_b = (const float*)d_in[2];
  const float* wq    = (const float*)d_in[3];
  const float* wk    = (const float*)d_in[4];
  const float* wv    = (const float*)d_in[5];
  const float* proj  = (const float*)d_in[6];
  const float* wo    = (const float*)d_in[7];
  const float* bo    = (const float*)d_in[8];
  const float* ln2_g = (const float*)d_in[9];
  const float* ln2_b = (const float*)d_in[10];
  const float* w1    = (const float*)d_in[11];
  const float* b1    = (const float*)d_in[12];
  const float* w2    = (const float*)d_in[13];
  const float* b2    = (const float*)d_in[14];
  float* out = (float*)d_out;
  (void)ws_size; (void)in_sizes; (void)n_in; (void)out_size;

  const size_t TOK = (size_t)Bc * Sc;           // 16384
  const size_t REG = TOK * Dc * sizeof(bf16);   // 32 MB
  char* ws = (char*)d_ws;
  bf16* R0 = (bf16*)(ws + 0 * REG);             // h -> kvpart -> h2
  bf16* R1 = (bf16*)(ws + 1 * REG);             // qf -> mid(spans R1+R2)
  bf16* R2 = (bf16*)(ws + 2 * REG);             // kf -> attn
  bf16* R3 = (bf16*)(ws + 3 * REG);             // v
  float* kvpart = (float*)R0;                                   // 16 MB (aliases R0, h dead)
  float* kspart = (float*)((char*)R0 + (size_t)64 * KVSPLIT * 4096 * 4);
  char* p = ws + 4 * REG;
  bf16* kvt   = (bf16*)p;                 p += (size_t)64 * 64 * 64 * 2;
  bf16* ksb16 = (bf16*)p;                 p += (size_t)64 * 64 * 2;
  bf16* wqt = (bf16*)p;                   p += (size_t)Dc * Dc * 2;   // wqpt/wkpt/wvt contiguous:
  bf16* wkt = (bf16*)p;                   p += (size_t)Dc * Dc * 2;   // single [3072][1024] Bt slab
  bf16* wvt = (bf16*)p;                   p += (size_t)Dc * Dc * 2;
  bf16* wot = (bf16*)p;                   p += (size_t)Dc * Dc * 2;
  bf16* w1t = (bf16*)p;                   p += (size_t)Dc * DFFc * 2;
  bf16* w2t = (bf16*)p;                   p += (size_t)Dc * DFFc * 2;

  dim3 blk(256);
  // 0. weight prep: fold proj into wq/wk (Bt form); transpose wv/wo/w1/w2
  tcvt_proj_kernel<<<dim3(Dc / 64, Hc, 2), blk, 0, stream>>>(wq, wk, proj, wqt, wkt);
  tcvt_kernel<<<dim3(Dc / 32, Dc / 32), blk, 0, stream>>>(wv, wvt, Dc, Dc);
  tcvt_kernel<<<dim3(Dc / 32, Dc / 32), blk, 0, stream>>>(wo, wot, Dc, Dc);
  tcvt_kernel<<<dim3(DFFc / 32, Dc / 32), blk, 0, stream>>>(w1, w1t, Dc, DFFc);
  tcvt_kernel<<<dim3(Dc / 32, DFFc / 32), blk, 0, stream>>>(w2, w2t, DFFc, Dc);

  // 1. h = LN1(x) -> R0
  ln_kernel<<<dim3(TOK), blk, 0, stream>>>(x, ln1_g, ln1_b, R0);

  // 2. fused QKV+featuremap: [TOK,1024] @ [3072,1024]^T, EPI=4:
  //    qf -> R1 (per-head, relu+eps), kf -> R2 (per-head, relu+eps), v -> R3
  dim3 gQKV(3072 / 128, TOK / 128);
  mgemm_kernel<4><<<gQKV, blk, 0, stream>>>((const ushort*)R0, (const ushort*)wqt, nullptr, nullptr,
                                            nullptr, R1, TOK, 3072, Dc, Dc, Dc);

  // 3. kv partials + reduce (kvpart aliases R0; h dead)
  kvp_mfma<<<dim3(KVSPLIT, Bc * Hc), blk, 0, stream>>>((const ushort*)R2, (const ushort*)R3,
                                                       kvpart, kspart);
  kvr_kernel<<<dim3(Bc * Hc), blk, 0, stream>>>(kvpart, kspart, kvt, ksb16);

  // 4. attn: qf(R1) x kvt -> R2 (kf dead)
  dim3 gF(Sc / 256, Hc, Bc);
  attn_mfma<<<gF, blk, 0, stream>>>((const ushort*)R1, (const ushort*)kvt,
                                    (const ushort*)ksb16, R2);

  // 5. x2 = x + attn @ wo + bo -> d_out (f32)
  dim3 gD(Dc / 128, TOK / 128);
  mgemm_kernel<1><<<gD, blk, 0, stream>>>((const ushort*)R2, (const ushort*)wot, bo, x,
                                          out, nullptr, TOK, Dc, Dc, Dc, Dc);

  // 6. h2 = LN2(x2) -> R0 (kvpart dead)
  ln_kernel<<<dim3(TOK), blk, 0, stream>>>(out, ln2_g, ln2_b, R0);

  // 7. FFN split by token halves: mid [8192,4096] bf16 spans R1+R2 (qf/attn dead)
  bf16* mid = R1;
  for (int half = 0; half < 2; ++half) {
    const ushort* a1 = (const ushort*)R0 + (size_t)half * 8192 * Dc;
    float* outh = out + (size_t)half * 8192 * Dc;
    mgemm_kernel<2><<<dim3(DFFc / 128, 8192 / 128), blk, 0, stream>>>(
        a1, (const ushort*)w1t, b1, nullptr, nullptr, mid, 8192, DFFc, Dc, Dc, Dc);
    mgemm_kernel<3><<<dim3(Dc / 128, 8192 / 128), blk, 0, stream>>>(
        (const ushort*)mid, (const ushort*)w2t, b2, outh, outh, nullptr,
        8192, Dc, DFFc, DFFc, DFFc);
  }
}